// Round 2
// baseline (113.135 us; speedup 1.0000x reference)
//
#include <hip/hip_runtime.h>

#define SEQ 512
#define BZ  64
#define DIN 1024
#define HID 256
#define DOUT 1024
#define NLANG 16

typedef __attribute__((ext_vector_type(8))) __bf16 bf16x8;
typedef __attribute__((ext_vector_type(4))) float f32x4;

__device__ __forceinline__ unsigned int f2bf_pack(float lo, float hi) {
    unsigned short a = __builtin_bit_cast(unsigned short, (__bf16)lo);
    unsigned short b = __builtin_bit_cast(unsigned short, (__bf16)hi);
    return (unsigned int)a | ((unsigned int)b << 16);
}

// Async global->LDS, 16B per lane. lds base must be wave-uniform; HW writes
// lane i's 16B at lds + i*16. Global pointer is per-lane.
__device__ __forceinline__ void gload_lds16(const unsigned short* g, unsigned short* l) {
    __builtin_amdgcn_global_load_lds(
        (const __attribute__((address_space(1))) unsigned int*)g,
        (__attribute__((address_space(3))) unsigned int*)l, 16, 0, 0);
}

// src f32 [L][R][C] (R = k dim, C = n dim) ->
// dst bf16 tiles [L][C/256 (nb)][R/64 (kt)][256 n][64 k], 16B-chunk slot = c ^ (n&7).
// grid = (L, R/64, C/64), block = 256.
__global__ __launch_bounds__(256)
void transpose_cvt_tile(const float* __restrict__ src, unsigned short* __restrict__ dst,
                        int R, int C) {
    __shared__ float tile[64][65];
    const int l  = blockIdx.x;
    const int rb = blockIdx.y * 64;
    const int cb = blockIdx.z * 64;
    const float* s = src + (long)l * R * C;
    const int t = threadIdx.x;
#pragma unroll
    for (int j = 0; j < 4; ++j) {
        int u = t + 256 * j;
        int r = u >> 4, c4 = u & 15;
        float4 v = *(const float4*)(s + (long)(rb + r) * C + cb + c4 * 4);
        tile[r][c4 * 4 + 0] = v.x; tile[r][c4 * 4 + 1] = v.y;
        tile[r][c4 * 4 + 2] = v.z; tile[r][c4 * 4 + 3] = v.w;
    }
    __syncthreads();
    const int NBl = C >> 8, KTl = R >> 6;
    const int nb = cb >> 8, kt = rb >> 6;
    unsigned short* dt = dst + (((long)l * NBl + nb) * KTl + kt) * 16384;
#pragma unroll
    for (int j = 0; j < 4; ++j) {
        int u = t + 256 * j;
        int dr = u >> 4, dc4 = u & 15;          // dr: n within this 64-col strip; dc4: k chunk of 4
        int n_t  = (cb & 255) + dr;             // n within 256-row tile
        int ch   = dc4 >> 1, half = dc4 & 1;    // 16B chunk, 8B half
        uint2 o;
        o.x = f2bf_pack(tile[dc4 * 4 + 0][dr], tile[dc4 * 4 + 1][dr]);
        o.y = f2bf_pack(tile[dc4 * 4 + 2][dr], tile[dc4 * 4 + 3][dr]);
        *(uint2*)(dt + n_t * 64 + ((ch ^ (n_t & 7)) << 3) + half * 4) = o;
    }
}

// out[s, n] = act( sum_k A[s, b, k] * W[lid, n, k] + bias[lid, n] )
// A tile 64x64, W tile 256n x 64k, 4 waves, each wave 64 rows x 64 cols,
// 4x4 frags of v_mfma_f32_16x16x32_bf16. W (and A when !AF32) staged via
// global_load_lds from pre-swizzled tile-major storage.
// grid = (BZ, SEQ/64, NTOT/256), block = 256.
template<int KTOT, int NTOT, bool AF32, bool L1RELU>
__global__ __launch_bounds__(256)
void mlp_gemm(const void* __restrict__ Ap,
              const unsigned short* __restrict__ Ws,   // [NLANG][NB][KT][256][64] swizzled bf16
              const float* __restrict__ bias,          // [NLANG][NTOT]
              const int* __restrict__ lang,            // [BZ]
              void* __restrict__ outp) {
    constexpr int KT = KTOT / 64;
    constexpr int NB = NTOT / 256;
    __shared__ unsigned short sA[64 * 64];    // 8 KiB
    __shared__ unsigned short sW[256 * 64];   // 32 KiB
    char* cA = (char*)sA;
    char* cW = (char*)sW;

    const int b    = blockIdx.x;
    const int st   = blockIdx.y;
    const int nblk = blockIdx.z;
    const int t    = threadIdx.x;
    const int lane = t & 63;
    const int w    = t >> 6;
    const int lid  = lang[b];
    const int s0   = st * 64;

    const float*          Af = (const float*)Ap;
    const long Abase = (long)s0 * BZ * KTOT + (long)b * KTOT;           // f32 path
    const unsigned short* At0 = (const unsigned short*)Ap
                                + ((long)b * (SEQ / 64) + st) * KT * 4096; // tiled bf16 path
    const unsigned short* Wt0 = Ws + (((long)lid * NB + nblk) * KT) * 16384;

    const f32x4 zero4 = {0.f, 0.f, 0.f, 0.f};
    f32x4 acc[4][4];
#pragma unroll
    for (int mi = 0; mi < 4; ++mi)
#pragma unroll
        for (int ni = 0; ni < 4; ++ni) acc[mi][ni] = zero4;

    for (int kt = 0; kt < KT; ++kt) {
        // ---- stage A tile [64][64] bf16 (swizzled content) ----
        if constexpr (AF32) {
#pragma unroll
            for (int j = 0; j < 4; ++j) {
                int u = t + 256 * j;
                int m = u >> 4, c4 = u & 15;
                const float4 v = *(const float4*)(Af + Abase + (long)m * (BZ * KTOT) + kt * 64 + c4 * 4);
                uint2 p;
                p.x = f2bf_pack(v.x, v.y);
                p.y = f2bf_pack(v.z, v.w);
                *(uint2*)(cA + (((m * 128) + c4 * 8) ^ ((m & 7) << 4))) = p;
            }
        } else {
            const unsigned short* At = At0 + kt * 4096;
#pragma unroll
            for (int j = 0; j < 2; ++j) {
                int seg = w * 2 + j;                       // 1KB segments
                gload_lds16(At + seg * 512 + lane * 8, sA + seg * 512);
            }
        }
        // ---- stage W tile [256][64] bf16 (pre-swizzled, linear copy) ----
        {
            const unsigned short* Wt = Wt0 + kt * 16384;
#pragma unroll
            for (int j = 0; j < 8; ++j) {
                int seg = w * 8 + j;
                gload_lds16(Wt + seg * 512 + lane * 8, sW + seg * 512);
            }
        }
        __syncthreads();

#pragma unroll
        for (int ks = 0; ks < 2; ++ks) {
            const int kb = (ks * 32 + ((lane >> 4) * 8)) * 2;   // byte offset in 128B row
            bf16x8 av[4], bv[4];
#pragma unroll
            for (int mi = 0; mi < 4; ++mi) {
                int r = mi * 16 + (lane & 15);
                av[mi] = __builtin_bit_cast(bf16x8,
                    *(const uint4*)(cA + ((r * 128 + kb) ^ ((r & 7) << 4))));
            }
#pragma unroll
            for (int ni = 0; ni < 4; ++ni) {
                int n = w * 64 + ni * 16 + (lane & 15);
                bv[ni] = __builtin_bit_cast(bf16x8,
                    *(const uint4*)(cW + ((n * 128 + kb) ^ ((n & 7) << 4))));
            }
#pragma unroll
            for (int mi = 0; mi < 4; ++mi)
#pragma unroll
                for (int ni = 0; ni < 4; ++ni)
                    acc[mi][ni] = __builtin_amdgcn_mfma_f32_16x16x32_bf16(
                        av[mi], bv[ni], acc[mi][ni], 0, 0, 0);
        }
        __syncthreads();
    }

    // ---- epilogue ----
    float bvv[4];
#pragma unroll
    for (int ni = 0; ni < 4; ++ni)
        bvv[ni] = bias[(long)lid * NTOT + nblk * 256 + w * 64 + ni * 16 + (lane & 15)];

#pragma unroll
    for (int mi = 0; mi < 4; ++mi) {
#pragma unroll
        for (int r = 0; r < 4; ++r) {
            const int row = mi * 16 + (lane >> 4) * 4 + r;
#pragma unroll
            for (int ni = 0; ni < 4; ++ni) {
                const int col = nblk * 256 + w * 64 + ni * 16 + (lane & 15);
                float v = acc[mi][ni][r] + bvv[ni];
                if constexpr (L1RELU) {
                    // write h in layer-2's tiled pre-swizzled A layout:
                    // [b][st][kt2][64 r][64 kk], chunk slot = c ^ (r&7)
                    v = v > 0.f ? v : 0.f;
                    int kt2 = col >> 6, kk = col & 63;
                    int ch = kk >> 3, e = kk & 7;
                    long idx = (((long)b * (SEQ / 64) + st) * (HID / 64) + kt2) * 4096
                             + row * 64 + ((ch ^ (row & 7)) << 3) + e;
                    ((unsigned short*)outp)[idx] =
                        __builtin_bit_cast(unsigned short, (__bf16)v);
                } else {
                    const long s = s0 + row;
                    ((float*)outp)[(s * BZ + b) * NTOT + col] = v;
                }
            }
        }
    }
}

extern "C" void kernel_launch(void* const* d_in, const int* in_sizes, int n_in,
                              void* d_out, int out_size, void* d_ws, size_t ws_size,
                              hipStream_t stream) {
    const float* x    = (const float*)d_in[0];
    const int*   lang = (const int*)d_in[1];
    const float* W1   = (const float*)d_in[2];
    const float* b1   = (const float*)d_in[3];
    const float* W2   = (const float*)d_in[4];
    const float* b2   = (const float*)d_in[5];
    float* y = (float*)d_out;

    // ws: W1s bf16 [16][1][16][256][64] | W2s bf16 [16][4][4][256][64] | h bf16 [64][8][4][64][64]
    const size_t w1s_bytes = (size_t)NLANG * HID * DIN * 2;    // 8 MiB
    const size_t w2s_bytes = (size_t)NLANG * DOUT * HID * 2;   // 8 MiB
    unsigned short* W1s = (unsigned short*)d_ws;
    unsigned short* W2s = (unsigned short*)((char*)d_ws + w1s_bytes);
    unsigned short* h   = (unsigned short*)((char*)d_ws + w1s_bytes + w2s_bytes);

    // prep: transpose + convert + tile + pre-swizzle weights
    transpose_cvt_tile<<<dim3(NLANG, DIN / 64, HID / 64), 256, 0, stream>>>(W1, W1s, DIN, HID);
    transpose_cvt_tile<<<dim3(NLANG, HID / 64, DOUT / 64), 256, 0, stream>>>(W2, W2s, HID, DOUT);

    // layer 1: h = relu(x @ W1 + b1)   [f32 in, tiled bf16 out]
    mlp_gemm<DIN, HID, true, true>
        <<<dim3(BZ, SEQ / 64, HID / 256), 256, 0, stream>>>(x, W1s, b1, lang, h);

    // layer 2: y = h @ W2 + b2          [tiled bf16 in, f32 out]
    mlp_gemm<HID, DOUT, false, false>
        <<<dim3(BZ, SEQ / 64, DOUT / 256), 256, 0, stream>>>(h, W2s, b2, lang, y);
}

// Round 3
// 102.329 us; speedup vs baseline: 1.1056x; 1.1056x over previous
//
#include <hip/hip_runtime.h>

#define SEQ 512
#define BZ  64
#define DIN 1024
#define HID 256
#define DOUT 1024
#define NLANG 16

typedef __attribute__((ext_vector_type(8))) __bf16 bf16x8;
typedef __attribute__((ext_vector_type(4))) float f32x4;

__device__ __forceinline__ unsigned short f2bf(float f) {
    return __builtin_bit_cast(unsigned short, (__bf16)f);
}
__device__ __forceinline__ unsigned int f2bf_pack(float lo, float hi) {
    return (unsigned int)f2bf(lo) | ((unsigned int)f2bf(hi) << 16);
}

// W[lid][K][N] f32  ->  Wf[lid][N/16][K/32][64 lanes][8] bf16 (fragment-major).
// Fragment (n16,k32), lane l, elem j  =  W[lid][k32*32+(l>>4)*8+j][n16*16+(l&15)].
// One thread per (fragment, lane): reads 8 strided f32, writes one coalesced uint4.
template<int K, int N>
__global__ __launch_bounds__(256)
void prep_frags(const float* __restrict__ src, unsigned short* __restrict__ dst) {
    constexpr int K32 = K / 32, N16 = N / 16;
    const int gid = blockIdx.x * 256 + threadIdx.x;
    const int l   = gid & 63;
    const int f   = gid >> 6;
    const int k32 = f & (K32 - 1);
    const int n16 = (f / K32) & (N16 - 1);
    const int lid = f / (K32 * N16);
    const float* s = src + ((long)lid * K + k32 * 32 + (l >> 4) * 8) * N + n16 * 16 + (l & 15);
    unsigned short o[8];
#pragma unroll
    for (int j = 0; j < 8; ++j) o[j] = f2bf(s[(long)j * N]);
    uint4 v;
    v.x = (unsigned int)o[0] | ((unsigned int)o[1] << 16);
    v.y = (unsigned int)o[2] | ((unsigned int)o[3] << 16);
    v.z = (unsigned int)o[4] | ((unsigned int)o[5] << 16);
    v.w = (unsigned int)o[6] | ((unsigned int)o[7] << 16);
    *(uint4*)(dst + (long)gid * 8) = v;
}

// Fused per-language MLP. One block per (b, st): 64 seq rows.
// Phase 1: h64x256 = relu(x64x1024 @ W1 + b1), acc in regs, h -> swizzled LDS.
// Phase 2: y64x1024 = h @ W2 + b2, A-frags from LDS (held in regs), B-frags
// straight from L2 (fragment-major W2f), no barriers.
__global__ __launch_bounds__(256, 2)
void fused_mlp(const float* __restrict__ x,
               const unsigned short* __restrict__ W1f,
               const float* __restrict__ b1,
               const unsigned short* __restrict__ W2f,
               const float* __restrict__ b2,
               const int* __restrict__ lang,
               float* __restrict__ y) {
    __shared__ unsigned short sA[2][64 * 64];   // 2 x 8 KiB x-tile (bf16, swizzled)
    __shared__ unsigned short sH[64 * 256];     // 32 KiB h-tile (bf16, swizzled)

    const int b  = blockIdx.x;
    const int st = blockIdx.y;
    const int t  = threadIdx.x;
    const int l  = t & 63;
    const int w  = t >> 6;
    const int lid = lang[b];
    const int s0  = st * 64;
    const long xbase = (long)s0 * BZ * DIN + (long)b * DIN;

    const f32x4 z4 = {0.f, 0.f, 0.f, 0.f};

    // ---------------- phase 1 ----------------
    f32x4 acc1[4][4];
#pragma unroll
    for (int mi = 0; mi < 4; ++mi)
#pragma unroll
        for (int ni = 0; ni < 4; ++ni) acc1[mi][ni] = z4;

    float4 xr[4];
#define LOADX(KT)                                                                 \
    {                                                                             \
        _Pragma("unroll")                                                         \
        for (int j = 0; j < 4; ++j) {                                             \
            int u = t + 256 * j, m = u >> 4, c4 = u & 15;                         \
            xr[j] = *(const float4*)(x + xbase + (long)m * (BZ * DIN) + (KT) * 64 + c4 * 4); \
        }                                                                         \
    }
#define WRITEX(BUF)                                                               \
    {                                                                             \
        char* cA = (char*)sA[BUF];                                                \
        _Pragma("unroll")                                                         \
        for (int j = 0; j < 4; ++j) {                                             \
            int u = t + 256 * j, m = u >> 4, c4 = u & 15;                         \
            uint2 p;                                                              \
            p.x = f2bf_pack(xr[j].x, xr[j].y);                                    \
            p.y = f2bf_pack(xr[j].z, xr[j].w);                                    \
            *(uint2*)(cA + (((m * 128) + c4 * 8) ^ ((m & 7) << 4))) = p;          \
        }                                                                         \
    }

    LOADX(0);
    WRITEX(0);
    __syncthreads();

    const unsigned short* w1p = W1f + (((long)lid * 16 + w * 4) * 32) * 512 + (long)l * 8;
    // strides (shorts): ni -> 32*512 = 16384 ; k32 (=kt*2+ks) -> 512

    for (int kt = 0; kt < 16; ++kt) {
        const int cur = kt & 1;
        if (kt < 15) LOADX(kt + 1);

        // B1 fragments for this kt (both ks), straight from L2
        bf16x8 bv[2][4];
#pragma unroll
        for (int ks = 0; ks < 2; ++ks)
#pragma unroll
            for (int ni = 0; ni < 4; ++ni)
                bv[ks][ni] = __builtin_bit_cast(bf16x8,
                    *(const uint4*)(w1p + (long)ni * 16384 + (kt * 2 + ks) * 512));

        char* cA = (char*)sA[cur];
#pragma unroll
        for (int ks = 0; ks < 2; ++ks) {
            bf16x8 av[4];
#pragma unroll
            for (int mi = 0; mi < 4; ++mi) {
                int row = mi * 16 + (l & 15);
                int ch  = ks * 4 + (l >> 4);
                av[mi] = __builtin_bit_cast(bf16x8,
                    *(const uint4*)(cA + row * 128 + ((ch ^ (row & 7)) << 4)));
            }
#pragma unroll
            for (int mi = 0; mi < 4; ++mi)
#pragma unroll
                for (int ni = 0; ni < 4; ++ni)
                    acc1[mi][ni] = __builtin_amdgcn_mfma_f32_16x16x32_bf16(
                        av[mi], bv[ks][ni], acc1[mi][ni], 0, 0, 0);
        }

        if (kt < 15) WRITEX(cur ^ 1);
        __syncthreads();
    }

    // epilogue 1: bias + relu + bf16 -> swizzled sH
    {
        float bvv[4];
#pragma unroll
        for (int ni = 0; ni < 4; ++ni)
            bvv[ni] = b1[lid * HID + w * 64 + ni * 16 + (l & 15)];
        char* cH = (char*)sH;
#pragma unroll
        for (int mi = 0; mi < 4; ++mi)
#pragma unroll
            for (int r = 0; r < 4; ++r) {
                int row = mi * 16 + (l >> 4) * 4 + r;
#pragma unroll
                for (int ni = 0; ni < 4; ++ni) {
                    int col = w * 64 + ni * 16 + (l & 15);
                    float v = acc1[mi][ni][r] + bvv[ni];
                    v = v > 0.f ? v : 0.f;
                    *(unsigned short*)(cH + row * 512 + (((col >> 3) ^ (row & 7)) << 4)
                                       + (col & 7) * 2) = f2bf(v);
                }
            }
    }
    __syncthreads();

    // ---------------- phase 2 ----------------
    // A-fragments: whole 64x256 h-tile, held in registers (128 VGPR)
    bf16x8 a2[4][8];
    {
        char* cH = (char*)sH;
#pragma unroll
        for (int mi = 0; mi < 4; ++mi)
#pragma unroll
            for (int ks = 0; ks < 8; ++ks) {
                int row = mi * 16 + (l & 15);
                int ch  = ks * 4 + (l >> 4);
                a2[mi][ks] = __builtin_bit_cast(bf16x8,
                    *(const uint4*)(cH + row * 512 + ((ch ^ (row & 7)) << 4)));
            }
    }

    const unsigned short* w2p = W2f + (((long)lid * 64 + w * 16) * 8) * 512 + (long)l * 8;
    // strides (shorts): n16 -> 8*512 = 4096 ; ks -> 512

#pragma unroll 1
    for (int nc = 0; nc < 4; ++nc) {
        f32x4 acc[4][4];
#pragma unroll
        for (int mi = 0; mi < 4; ++mi)
#pragma unroll
            for (int ni = 0; ni < 4; ++ni) acc[mi][ni] = z4;

        const unsigned short* wp = w2p + (long)nc * 4 * 4096;

        // ping-pong prefetch of B2 fragments over ks
        bf16x8 pv[2][4];
#pragma unroll
        for (int ni = 0; ni < 4; ++ni)
            pv[0][ni] = __builtin_bit_cast(bf16x8, *(const uint4*)(wp + (long)ni * 4096));
#pragma unroll
        for (int ks = 0; ks < 8; ++ks) {
            const int cb = ks & 1;
            if (ks < 7) {
#pragma unroll
                for (int ni = 0; ni < 4; ++ni)
                    pv[cb ^ 1][ni] = __builtin_bit_cast(bf16x8,
                        *(const uint4*)(wp + (long)ni * 4096 + (ks + 1) * 512));
            }
#pragma unroll
            for (int mi = 0; mi < 4; ++mi)
#pragma unroll
                for (int ni = 0; ni < 4; ++ni)
                    acc[mi][ni] = __builtin_amdgcn_mfma_f32_16x16x32_bf16(
                        a2[mi][ks], pv[cb][ni], acc[mi][ni], 0, 0, 0);
        }

        float b2v[4];
#pragma unroll
        for (int ni = 0; ni < 4; ++ni)
            b2v[ni] = b2[lid * DOUT + w * 256 + nc * 64 + ni * 16 + (l & 15)];
#pragma unroll
        for (int mi = 0; mi < 4; ++mi)
#pragma unroll
            for (int r = 0; r < 4; ++r) {
                int row = mi * 16 + (l >> 4) * 4 + r;
#pragma unroll
                for (int ni = 0; ni < 4; ++ni) {
                    int col = w * 256 + nc * 64 + ni * 16 + (l & 15);
                    y[((long)(s0 + row) * BZ + b) * DOUT + col] = acc[mi][ni][r] + b2v[ni];
                }
            }
    }
#undef LOADX
#undef WRITEX
}

extern "C" void kernel_launch(void* const* d_in, const int* in_sizes, int n_in,
                              void* d_out, int out_size, void* d_ws, size_t ws_size,
                              hipStream_t stream) {
    const float* x    = (const float*)d_in[0];
    const int*   lang = (const int*)d_in[1];
    const float* W1   = (const float*)d_in[2];
    const float* b1   = (const float*)d_in[3];
    const float* W2   = (const float*)d_in[4];
    const float* b2   = (const float*)d_in[5];
    float* y = (float*)d_out;

    // ws: W1f bf16 [16][16][32][64][8] (8 MiB) | W2f bf16 [16][64][8][64][8] (8 MiB)
    unsigned short* W1f = (unsigned short*)d_ws;
    unsigned short* W2f = (unsigned short*)((char*)d_ws + (size_t)NLANG * HID * DIN * 2);

    prep_frags<DIN, HID><<<2048, 256, 0, stream>>>(W1, W1f);
    prep_frags<HID, DOUT><<<2048, 256, 0, stream>>>(W2, W2f);

    fused_mlp<<<dim3(BZ, SEQ / 64), 256, 0, stream>>>(x, W1f, b1, W2f, b2, lang, y);
}